// Round 1
// 143.600 us; speedup vs baseline: 1.0476x; 1.0476x over previous
//
#include <hip/hip_runtime.h>
#include <hip/hip_bf16.h>

#define B_N     2048
#define IN_N    512
#define SEQ_N   128
#define HID_N   12
#define HP_N    16
#define OUT_N   3

typedef __attribute__((ext_vector_type(8))) short short8;
typedef __attribute__((ext_vector_type(4))) float f32x4;
typedef unsigned int uint;
typedef unsigned short ushort;

__device__ __forceinline__ float fast_tanh(float x) {
    float e = __builtin_amdgcn_exp2f(x * 2.8853900817779268f);
    return 1.0f - 2.0f * __builtin_amdgcn_rcpf(e + 1.0f);
}

__device__ __forceinline__ ushort f2bf(float f) {   // RNE fp32->bf16
    uint u = __float_as_uint(f);
    u += 0x7fffu + ((u >> 16) & 1u);
    return (ushort)(u >> 16);
}

__device__ __forceinline__ float bf2f(ushort s) {
    return __uint_as_float(((uint)s) << 16);
}

// ---------------------------------------------------------------------------
// Prep: emb (512x128 f32) -> embB bf16; wBT[16][512] = zero-padded w_ih_f.
// ---------------------------------------------------------------------------
__global__ __launch_bounds__(256) void k_prep(
    const float* __restrict__ emb, const float* __restrict__ w_ih_f,
    ushort* __restrict__ embB, ushort* __restrict__ wBT)
{
    int tid = blockIdx.x * 256 + threadIdx.x;      // 0..16383
    float4 e = ((const float4*)emb)[tid];
    uint2 o;
    o.x = (uint)f2bf(e.x) | ((uint)f2bf(e.y) << 16);
    o.y = (uint)f2bf(e.z) | ((uint)f2bf(e.w) << 16);
    ((uint2*)embB)[tid] = o;
    if (tid < 16 * IN_N)
        wBT[tid] = (tid < HID_N * IN_N) ? f2bf(w_ih_f[tid]) : (ushort)0;
}

// ---------------------------------------------------------------------------
// k_pre: per-b GEMM  preB[b][s][h] = sum_i embB[xb[i]][s] * wBT[h][i]
// via mfma_f32_16x16x32_bf16.  One block per b, 256 threads (4 waves).
//
// Gather is COALESCED: per load instruction, 16 consecutive lanes read one
// row's contiguous 256B (16 lines/instr instead of 64 scattered lines).
// Thread (w, rg=quad, sw=lane16) holds rows i = w*32+rg*8 .. +7 at s-window
// [sw*8, sw*8+8).  Pack: per s, 4x v_perm -> 1 ds_write_b128 (granule
// 8*(sw&3)+17p+4w+rg -> <=4-way on 8 writes only; reads unchanged, stride
// 136 ushorts).  Next chunk's gather issued right after pack (WAR-safe) so
// L2 latency hides under barrier+MFMA of the current chunk.
// ---------------------------------------------------------------------------
__global__ __launch_bounds__(256, 4) void k_pre(
    const int* __restrict__ x, const ushort* __restrict__ embB,
    const ushort* __restrict__ wBT, ushort* __restrict__ preB)
{
    __shared__ int xb[IN_N];
    __shared__ __align__(16) ushort As[128 * 136];

    const int t = threadIdx.x;
    const int b = blockIdx.x;

    ((int2*)xb)[t] = ((const int2*)(x + b * IN_N))[t];
    __syncthreads();

    const int l      = t & 63;
    const int w      = t >> 6;        // wave 0..3
    const int lane16 = l & 15;        // gather/pack: 16B s-window; mfma: A-row
    const int quad   = l >> 4;        // gather/pack: row-group;   mfma: k-quad
    const int il     = w * 32 + quad * 8;   // i-position of this thread's 8 rows

    f32x4 acc[2] = {{0.f,0.f,0.f,0.f},{0.f,0.f,0.f,0.f}};

    uint R[8][4];

    // prologue: gather chunk 0 (8 rows x 16B per thread, coalesced)
    #pragma unroll
    for (int j = 0; j < 8; ++j) {
        const uint4 v = *(const uint4*)(embB + (size_t)xb[il + j] * SEQ_N + lane16 * 8);
        R[j][0] = v.x; R[j][1] = v.y; R[j][2] = v.z; R[j][3] = v.w;
    }

    for (int c = 0; c < 4; ++c) {
        // B fragments for this chunk (wBT 16KB, L1-resident)
        short8 bfr[4];
        #pragma unroll
        for (int ks = 0; ks < 4; ++ks)
            bfr[ks] = *(const short8*)(wBT + lane16 * IN_N + c * 128 + ks * 32 + quad * 8);

        if (c) __syncthreads();   // all waves done reading previous As

        // transpose-pack: As[s = lane16*8+p][il..il+7] <- element p of 8 rows
        #pragma unroll
        for (int p = 0; p < 8; ++p) {
            const uint sel = (p & 1) ? 0x07060302u : 0x05040100u;
            const int pv = p >> 1;
            uint u0 = __builtin_amdgcn_perm(R[1][pv], R[0][pv], sel);
            uint u1 = __builtin_amdgcn_perm(R[3][pv], R[2][pv], sel);
            uint u2 = __builtin_amdgcn_perm(R[5][pv], R[4][pv], sel);
            uint u3 = __builtin_amdgcn_perm(R[7][pv], R[6][pv], sel);
            *(uint4*)&As[(size_t)(lane16 * 8 + p) * 136 + il] =
                make_uint4(u0, u1, u2, u3);
        }

        // issue next chunk's gather NOW: latency hides under barrier + MFMA
        if (c < 3) {
            const int ibase = (c + 1) * 128 + il;
            #pragma unroll
            for (int j = 0; j < 8; ++j) {
                const uint4 v = *(const uint4*)(embB + (size_t)xb[ibase + j] * SEQ_N + lane16 * 8);
                R[j][0] = v.x; R[j][1] = v.y; R[j][2] = v.z; R[j][3] = v.w;
            }
        }
        __syncthreads();

        // MFMA: 2 s-tiles per wave, 4 K-steps per chunk
        #pragma unroll
        for (int tt = 0; tt < 2; ++tt) {
            const int row = (w * 2 + tt) * 16 + lane16;
            #pragma unroll
            for (int ks = 0; ks < 4; ++ks) {
                short8 af = *(const short8*)&As[row * 136 + ks * 32 + quad * 8];
                acc[tt] = __builtin_amdgcn_mfma_f32_16x16x32_bf16(af, bfr[ks], acc[tt], 0, 0, 0);
            }
        }
    }

    // epilogue: D[m][n]: n = lane16 (=h), m = quad*4 + r (s within tile)
    if (lane16 < HID_N) {
        #pragma unroll
        for (int tt = 0; tt < 2; ++tt) {
            #pragma unroll
            for (int r = 0; r < 4; ++r) {
                int s = (w * 2 + tt) * 16 + quad * 4 + r;
                preB[((size_t)b * SEQ_N + s) * HP_N + lane16] = f2bf(acc[tt][r]);
            }
        }
    }
}

// ---------------------------------------------------------------------------
// k_rev: rev[b][h] = tanh( sum_i emb[x[b,i],127]*w_ih_r[h,i] + b_ih_r + b_hh_r )
// ---------------------------------------------------------------------------
__global__ __launch_bounds__(256) void k_rev(
    const int* __restrict__ x, const float* __restrict__ emb,
    const float* __restrict__ w_ih_r,
    const float* __restrict__ b_ih_r, const float* __restrict__ b_hh_r,
    float* __restrict__ rev)
{
    const int b = blockIdx.x * 4 + (threadIdx.x >> 6);
    const int l = threadIdx.x & 63;

    float p[12];
    #pragma unroll
    for (int h = 0; h < 12; ++h) p[h] = 0.f;

    for (int k = 0; k < 8; ++k) {
        int i = l + k * 64;
        int r = x[b * IN_N + i];
        float ev = emb[r * SEQ_N + 127];
        #pragma unroll
        for (int h = 0; h < 12; ++h) p[h] += ev * w_ih_r[h * IN_N + i];
    }
    #pragma unroll
    for (int off = 32; off; off >>= 1) {
        #pragma unroll
        for (int h = 0; h < 12; ++h) p[h] += __shfl_xor(p[h], off);
    }
    if (l == 0) {
        #pragma unroll
        for (int h = 0; h < 12; ++h)
            rev[b * HP_N + h] = fast_tanh(p[h] + b_ih_r[h] + b_hh_r[h]);
        #pragma unroll
        for (int h = 12; h < 16; ++h) rev[b * HP_N + h] = 0.f;
    }
}

// ---------------------------------------------------------------------------
// k_rnn: 16 lanes per b (lane j owns hidden j), h broadcast via ds_bpermute
// (no LDS round-trip). 256 thr = 16 b per block, 128 blocks.
// ---------------------------------------------------------------------------
__global__ __launch_bounds__(256) void k_rnn(
    const ushort* __restrict__ preB, const float* __restrict__ rev,
    const float* __restrict__ w_hh_f,
    const float* __restrict__ b_ih_f, const float* __restrict__ b_hh_f,
    const float* __restrict__ fc_w, const float* __restrict__ fc_b,
    float* __restrict__ out)
{
    __shared__ float ho[16][40];

    const int tid = threadIdx.x;
    const int l   = tid & 63;
    const int j   = l & 15;
    const int jj  = (j < 12) ? j : 0;
    const int gid = tid >> 4;                 // 0..15 in block
    const int b   = blockIdx.x * 16 + gid;
    const int baseaddr = (l & 48) << 2;       // group-base lane * 4

    const float4* wr = (const float4*)(w_hh_f + jj * 12);
    float4 w0 = wr[0], w1 = wr[1], w2 = wr[2];
    float W[12] = {w0.x, w0.y, w0.z, w0.w, w1.x, w1.y, w1.z, w1.w,
                   w2.x, w2.y, w2.z, w2.w};
    const float bias = b_ih_f[jj] + b_hh_f[jj];

    const ushort* pb = preB + (size_t)b * SEQ_N * HP_N + j;
    ushort pq[8];
    #pragma unroll
    for (int k = 0; k < 8; ++k) pq[k] = pb[k * HP_N];

    float h = 0.f;
    for (int s8 = 0; s8 < 16; ++s8) {
        #pragma unroll
        for (int k = 0; k < 8; ++k) {
            int s = s8 * 8 + k;
            float p = bf2f(pq[k]) + bias;
            pq[k] = pb[((s + 8) & 127) * HP_N];     // branchless prefetch
            int hb = __float_as_int(h);
            float hk[12];
            #pragma unroll
            for (int kk = 0; kk < 12; ++kk)
                hk[kk] = __int_as_float(__builtin_amdgcn_ds_bpermute(baseaddr + 4 * kk, hb));
            float c0 = p, c1 = 0.f, c2 = 0.f;
            #pragma unroll
            for (int u = 0; u < 4; ++u) {
                c0 = __builtin_fmaf(W[u],     hk[u],     c0);
                c1 = __builtin_fmaf(W[4 + u], hk[4 + u], c1);
                c2 = __builtin_fmaf(W[8 + u], hk[8 + u], c2);
            }
            h = fast_tanh(c0 + c1 + c2);
        }
    }

    // epilogue FC (intra-wave LDS, no barrier needed)
    ho[gid][j]      = h;
    ho[gid][20 + j] = rev[b * HP_N + j];
    if (j < OUT_N) {
        const float* fw = fc_w + j * 24;
        float o = fc_b[j];
        #pragma unroll
        for (int k = 0; k < 12; ++k)
            o += fw[k] * ho[gid][k] + fw[12 + k] * ho[gid][20 + k];
        out[b * OUT_N + j] = o;
    }
}

// ---------------------------------------------------------------------------
extern "C" void kernel_launch(void* const* d_in, const int* in_sizes, int n_in,
                              void* d_out, int out_size, void* d_ws, size_t ws_size,
                              hipStream_t stream) {
    const int*   x      = (const int*)  d_in[0];
    const float* emb    = (const float*)d_in[1];
    const float* w_ih_f = (const float*)d_in[2];
    const float* w_hh_f = (const float*)d_in[3];
    const float* b_ih_f = (const float*)d_in[4];
    const float* b_hh_f = (const float*)d_in[5];
    const float* w_ih_r = (const float*)d_in[6];
    const float* b_ih_r = (const float*)d_in[8];
    const float* b_hh_r = (const float*)d_in[9];
    const float* fc_w   = (const float*)d_in[10];
    const float* fc_b   = (const float*)d_in[11];
    float* out = (float*)d_out;

    ushort* preB = (ushort*)d_ws;                              // 8 MB
    float*  rev  = (float*)((char*)d_ws + 8388608);            // 128 KB
    ushort* embB = (ushort*)((char*)d_ws + 8519680);           // 128 KB
    ushort* wBT  = (ushort*)((char*)d_ws + 8650752);           // 16 KB

    k_prep<<<64,   256, 0, stream>>>(emb, w_ih_f, embB, wBT);
    k_pre <<<B_N,  256, 0, stream>>>(x, embB, wBT, preB);
    k_rev <<<B_N/4,256, 0, stream>>>(x, emb, w_ih_r, b_ih_r, b_hh_r, rev);
    k_rnn <<<B_N/16,256,0, stream>>>(preB, rev, w_hh_f, b_ih_f, b_hh_f, fc_w, fc_b, out);
}

// Round 2
// 138.227 us; speedup vs baseline: 1.0883x; 1.0389x over previous
//
#include <hip/hip_runtime.h>
#include <hip/hip_bf16.h>

#define B_N     2048
#define IN_N    512
#define SEQ_N   128
#define HID_N   12
#define HP_N    16
#define OUT_N   3

typedef __attribute__((ext_vector_type(8))) short short8;
typedef __attribute__((ext_vector_type(4))) float f32x4;
typedef unsigned int uint;
typedef unsigned short ushort;

__device__ __forceinline__ float fast_tanh(float x) {
    float e = __builtin_amdgcn_exp2f(x * 2.8853900817779268f);
    return 1.0f - 2.0f * __builtin_amdgcn_rcpf(e + 1.0f);
}

__device__ __forceinline__ ushort f2bf(float f) {   // RNE fp32->bf16
    uint u = __float_as_uint(f);
    u += 0x7fffu + ((u >> 16) & 1u);
    return (ushort)(u >> 16);
}

__device__ __forceinline__ float bf2f(ushort s) {
    return __uint_as_float(((uint)s) << 16);
}

// ---------------------------------------------------------------------------
// Prep: emb (512x128 f32) -> embB bf16; wBT[16][512] = zero-padded w_ih_f,
// wRT[16][512] = zero-padded w_ih_r.
// ---------------------------------------------------------------------------
__global__ __launch_bounds__(256) void k_prep(
    const float* __restrict__ emb, const float* __restrict__ w_ih_f,
    const float* __restrict__ w_ih_r,
    ushort* __restrict__ embB, ushort* __restrict__ wBT, ushort* __restrict__ wRT)
{
    int tid = blockIdx.x * 256 + threadIdx.x;      // 0..16383
    float4 e = ((const float4*)emb)[tid];
    uint2 o;
    o.x = (uint)f2bf(e.x) | ((uint)f2bf(e.y) << 16);
    o.y = (uint)f2bf(e.z) | ((uint)f2bf(e.w) << 16);
    ((uint2*)embB)[tid] = o;
    if (tid < 16 * IN_N) {
        bool live = tid < HID_N * IN_N;
        wBT[tid] = live ? f2bf(w_ih_f[tid]) : (ushort)0;
        wRT[tid] = live ? f2bf(w_ih_r[tid]) : (ushort)0;
    }
}

// ---------------------------------------------------------------------------
// k_pre: per-b GEMM  preB[b][s][h] = sum_i embB[xb[i]][s] * wBT[h][i]
// via mfma_f32_16x16x32_bf16.  One block per b, 256 threads (4 waves),
// __launch_bounds__(256,2): 128-VGPR budget (no spills), 2 blocks/CU.
//
// Gather coalesced: 16 consecutive lanes read one row's contiguous 256B.
// As layout: [128 s][128 i] bf16 with 16B-granule XOR swizzle
//   addr_ushort(s,i) = s*128 + ((i>>3) ^ ((s>>3)&7))*8 + (i&7)
// -> both ds_write_b128 (pack) and ds_read_b128 (A-frag) are 8-slot
// balanced = conflict-free (round-0/1 layouts had 8/16-way conflicts).
//
// k_rev is FOLDED in: the A-tile contains s=127 for all i, so a second
// B-operand (wRT) + accumulator yields rev[b][h] with +4 MFMA/chunk.
// ---------------------------------------------------------------------------
__global__ __launch_bounds__(256, 2) void k_pre(
    const int* __restrict__ x, const ushort* __restrict__ embB,
    const ushort* __restrict__ wBT, const ushort* __restrict__ wRT,
    const float* __restrict__ b_ih_r, const float* __restrict__ b_hh_r,
    ushort* __restrict__ preB, float* __restrict__ rev)
{
    __shared__ int xb[IN_N];
    __shared__ __align__(16) ushort As[128 * 128];

    const int t = threadIdx.x;
    const int b = blockIdx.x;

    ((int2*)xb)[t] = ((const int2*)(x + b * IN_N))[t];
    __syncthreads();

    const int l      = t & 63;
    const int w      = t >> 6;        // wave 0..3
    const int lane16 = l & 15;        // gather/pack: 16B s-window; mfma: A-row
    const int quad   = l >> 4;        // gather/pack: row-group;   mfma: k-quad
    const int il     = w * 32 + quad * 8;   // i-position of this thread's 8 rows
    const int wg     = w * 4 + quad;        // write granule (il>>3)
    const int wsx    = lane16 & 7;          // write-side (s>>3)&7

    f32x4 acc[2] = {{0.f,0.f,0.f,0.f},{0.f,0.f,0.f,0.f}};
    f32x4 accR   = {0.f,0.f,0.f,0.f};

    uint R[8][4];

    // prologue: gather chunk 0 (8 rows x 16B per thread, coalesced)
    #pragma unroll
    for (int j = 0; j < 8; ++j) {
        const uint4 v = *(const uint4*)(embB + (size_t)xb[il + j] * SEQ_N + lane16 * 8);
        R[j][0] = v.x; R[j][1] = v.y; R[j][2] = v.z; R[j][3] = v.w;
    }

    for (int c = 0; c < 4; ++c) {
        // B fragments for this chunk (wBT/wRT 32KB total, cache-resident)
        short8 bfr[4], bfrR[4];
        #pragma unroll
        for (int ks = 0; ks < 4; ++ks) {
            bfr[ks]  = *(const short8*)(wBT + lane16 * IN_N + c * 128 + ks * 32 + quad * 8);
            bfrR[ks] = *(const short8*)(wRT + lane16 * IN_N + c * 128 + ks * 32 + quad * 8);
        }

        if (c) __syncthreads();   // all waves done reading previous As

        // transpose-pack: As[s = lane16*8+p][il..il+7] <- element p of 8 rows
        #pragma unroll
        for (int p = 0; p < 8; ++p) {
            const uint sel = (p & 1) ? 0x07060302u : 0x05040100u;
            const int pv = p >> 1;
            uint u0 = __builtin_amdgcn_perm(R[1][pv], R[0][pv], sel);
            uint u1 = __builtin_amdgcn_perm(R[3][pv], R[2][pv], sel);
            uint u2 = __builtin_amdgcn_perm(R[5][pv], R[4][pv], sel);
            uint u3 = __builtin_amdgcn_perm(R[7][pv], R[6][pv], sel);
            const int s = lane16 * 8 + p;
            *(uint4*)&As[(size_t)s * 128 + (size_t)(wg ^ wsx) * 8] =
                make_uint4(u0, u1, u2, u3);
        }

        // issue next chunk's gather NOW: latency hides under barrier + MFMA
        if (c < 3) {
            const int ibase = (c + 1) * 128 + il;
            #pragma unroll
            for (int j = 0; j < 8; ++j) {
                const uint4 v = *(const uint4*)(embB + (size_t)xb[ibase + j] * SEQ_N + lane16 * 8);
                R[j][0] = v.x; R[j][1] = v.y; R[j][2] = v.z; R[j][3] = v.w;
            }
        }
        __syncthreads();

        // MFMA: 2 s-tiles per wave, 4 K-steps per chunk (+rev tile on tt=1)
        #pragma unroll
        for (int tt = 0; tt < 2; ++tt) {
            const int row = (w * 2 + tt) * 16 + lane16;
            const int rsx = (row >> 3) & 7;
            #pragma unroll
            for (int ks = 0; ks < 4; ++ks) {
                short8 af = *(const short8*)&As[(size_t)row * 128 +
                                                (size_t)(((ks * 4 + quad) ^ rsx)) * 8];
                acc[tt] = __builtin_amdgcn_mfma_f32_16x16x32_bf16(af, bfr[ks], acc[tt], 0, 0, 0);
                if (tt == 1)
                    accR = __builtin_amdgcn_mfma_f32_16x16x32_bf16(af, bfrR[ks], accR, 0, 0, 0);
            }
        }
    }

    // epilogue: D[m][n]: n = lane16 (=h), m = quad*4 + r (s within tile)
    if (lane16 < HID_N) {
        #pragma unroll
        for (int tt = 0; tt < 2; ++tt) {
            #pragma unroll
            for (int r = 0; r < 4; ++r) {
                int s = (w * 2 + tt) * 16 + quad * 4 + r;
                preB[((size_t)b * SEQ_N + s) * HP_N + lane16] = f2bf(acc[tt][r]);
            }
        }
        // rev: s=127 lives in wave 3's tt=1 tile at m=15 (quad=3, r=3)
        if (w == 3 && quad == 3)
            rev[b * HP_N + lane16] =
                fast_tanh(accR[3] + b_ih_r[lane16] + b_hh_r[lane16]);
    }
}

// ---------------------------------------------------------------------------
// k_rnn: 16 lanes per b (lane j owns hidden j), h broadcast via ds_bpermute
// (no LDS round-trip). 256 thr = 16 b per block, 128 blocks.
// ---------------------------------------------------------------------------
__global__ __launch_bounds__(256) void k_rnn(
    const ushort* __restrict__ preB, const float* __restrict__ rev,
    const float* __restrict__ w_hh_f,
    const float* __restrict__ b_ih_f, const float* __restrict__ b_hh_f,
    const float* __restrict__ fc_w, const float* __restrict__ fc_b,
    float* __restrict__ out)
{
    __shared__ float ho[16][40];

    const int tid = threadIdx.x;
    const int l   = tid & 63;
    const int j   = l & 15;
    const int jj  = (j < 12) ? j : 0;
    const int gid = tid >> 4;                 // 0..15 in block
    const int b   = blockIdx.x * 16 + gid;
    const int baseaddr = (l & 48) << 2;       // group-base lane * 4

    const float4* wr = (const float4*)(w_hh_f + jj * 12);
    float4 w0 = wr[0], w1 = wr[1], w2 = wr[2];
    float W[12] = {w0.x, w0.y, w0.z, w0.w, w1.x, w1.y, w1.z, w1.w,
                   w2.x, w2.y, w2.z, w2.w};
    const float bias = b_ih_f[jj] + b_hh_f[jj];

    const ushort* pb = preB + (size_t)b * SEQ_N * HP_N + j;
    ushort pq[8];
    #pragma unroll
    for (int k = 0; k < 8; ++k) pq[k] = pb[k * HP_N];

    float h = 0.f;
    for (int s8 = 0; s8 < 16; ++s8) {
        #pragma unroll
        for (int k = 0; k < 8; ++k) {
            int s = s8 * 8 + k;
            float p = bf2f(pq[k]) + bias;
            pq[k] = pb[((s + 8) & 127) * HP_N];     // branchless prefetch
            int hb = __float_as_int(h);
            float hk[12];
            #pragma unroll
            for (int kk = 0; kk < 12; ++kk)
                hk[kk] = __int_as_float(__builtin_amdgcn_ds_bpermute(baseaddr + 4 * kk, hb));
            float c0 = p, c1 = 0.f, c2 = 0.f;
            #pragma unroll
            for (int u = 0; u < 4; ++u) {
                c0 = __builtin_fmaf(W[u],     hk[u],     c0);
                c1 = __builtin_fmaf(W[4 + u], hk[4 + u], c1);
                c2 = __builtin_fmaf(W[8 + u], hk[8 + u], c2);
            }
            h = fast_tanh(c0 + c1 + c2);
        }
    }

    // epilogue FC (intra-wave LDS, no barrier needed)
    ho[gid][j]      = h;
    ho[gid][20 + j] = rev[b * HP_N + j];
    if (j < OUT_N) {
        const float* fw = fc_w + j * 24;
        float o = fc_b[j];
        #pragma unroll
        for (int k = 0; k < 12; ++k)
            o += fw[k] * ho[gid][k] + fw[12 + k] * ho[gid][20 + k];
        out[b * OUT_N + j] = o;
    }
}

// ---------------------------------------------------------------------------
extern "C" void kernel_launch(void* const* d_in, const int* in_sizes, int n_in,
                              void* d_out, int out_size, void* d_ws, size_t ws_size,
                              hipStream_t stream) {
    const int*   x      = (const int*)  d_in[0];
    const float* emb    = (const float*)d_in[1];
    const float* w_ih_f = (const float*)d_in[2];
    const float* w_hh_f = (const float*)d_in[3];
    const float* b_ih_f = (const float*)d_in[4];
    const float* b_hh_f = (const float*)d_in[5];
    const float* w_ih_r = (const float*)d_in[6];
    const float* b_ih_r = (const float*)d_in[8];
    const float* b_hh_r = (const float*)d_in[9];
    const float* fc_w   = (const float*)d_in[10];
    const float* fc_b   = (const float*)d_in[11];
    float* out = (float*)d_out;

    ushort* preB = (ushort*)d_ws;                              // 8 MB
    float*  rev  = (float*)((char*)d_ws + 8388608);            // 128 KB
    ushort* embB = (ushort*)((char*)d_ws + 8519680);           // 128 KB
    ushort* wBT  = (ushort*)((char*)d_ws + 8650752);           // 16 KB
    ushort* wRT  = (ushort*)((char*)d_ws + 8667136);           // 16 KB

    k_prep<<<64,   256, 0, stream>>>(emb, w_ih_f, w_ih_r, embB, wBT, wRT);
    k_pre <<<B_N,  256, 0, stream>>>(x, embB, wBT, wRT, b_ih_r, b_hh_r, preB, rev);
    k_rnn <<<B_N/16,256,0, stream>>>(preB, rev, w_hh_f, b_ih_f, b_hh_f, fc_w, fc_b, out);
}

// Round 3
// 127.102 us; speedup vs baseline: 1.1836x; 1.0875x over previous
//
#include <hip/hip_runtime.h>
#include <hip/hip_bf16.h>

#define B_N     2048
#define IN_N    512
#define SEQ_N   128
#define HID_N   12
#define HP_N    16
#define OUT_N   3

typedef __attribute__((ext_vector_type(8))) short short8;
typedef __attribute__((ext_vector_type(4))) float f32x4;
typedef unsigned int uint;
typedef unsigned short ushort;

__device__ __forceinline__ float fast_tanh(float x) {
    float e = __builtin_amdgcn_exp2f(x * 2.8853900817779268f);
    return 1.0f - 2.0f * __builtin_amdgcn_rcpf(e + 1.0f);
}

__device__ __forceinline__ ushort f2bf(float f) {   // RNE fp32->bf16
    uint u = __float_as_uint(f);
    u += 0x7fffu + ((u >> 16) & 1u);
    return (ushort)(u >> 16);
}

__device__ __forceinline__ float bf2f(ushort s) {
    return __uint_as_float(((uint)s) << 16);
}

// ---------------------------------------------------------------------------
// Prep: emb (512x128 f32) -> embB bf16;
// wP = B-fragments of w_ih_f / w_ih_r pre-packed in MFMA lane order:
//   wP[cks][src][l][j]  (cks = c*4+ks, src 0=fwd 1=rev, l = wave lane 0..63,
//   j 0..7), value = w[h = l&15][i = (cks>>2)*128 + (cks&3)*32 + (l>>4)*8 + j],
//   zero-padded for h >= 12.  k_pre then loads one coalesced dwordx4 per
//   lane per (c,ks) instead of 16-line scattered row reads.
// ---------------------------------------------------------------------------
__global__ __launch_bounds__(256) void k_prep(
    const float* __restrict__ emb, const float* __restrict__ w_ih_f,
    const float* __restrict__ w_ih_r,
    ushort* __restrict__ embB, ushort* __restrict__ wP)
{
    int tid = blockIdx.x * 256 + threadIdx.x;      // 0..16383
    float4 e = ((const float4*)emb)[tid];
    uint2 o;
    o.x = (uint)f2bf(e.x) | ((uint)f2bf(e.y) << 16);
    o.y = (uint)f2bf(e.z) | ((uint)f2bf(e.w) << 16);
    ((uint2*)embB)[tid] = o;

    // fragment pack: exactly one element per thread (16384 = 16*2*64*8)
    int j   = tid & 7;
    int l   = (tid >> 3) & 63;
    int src = (tid >> 9) & 1;
    int cks = tid >> 10;                           // 0..15
    int h   = l & 15;
    int i   = (cks >> 2) * 128 + (cks & 3) * 32 + (l >> 4) * 8 + j;
    const float* wsrc = src ? w_ih_r : w_ih_f;
    wP[(((size_t)cks * 2 + src) * 64 + l) * 8 + j] =
        (h < HID_N) ? f2bf(wsrc[h * IN_N + i]) : (ushort)0;
}

// ---------------------------------------------------------------------------
// k_pre: per-b GEMM  preB[b][s][h] = sum_i embB[xb[i]][s] * w_ih_f[h][i]
// via mfma_f32_16x16x32_bf16.  One block per b, 256 threads (4 waves).
//
// Gather coalesced: 16 consecutive lanes read one row's contiguous 256B.
// As layout: [128 s][16 granules of 8 ushorts], granule XOR-swizzled:
//   slot(s, igran) = igran ^ (s&7) ^ ((s>>3)&7)
// Write phases (s = lane16*8+p): slot = wg ^ p ^ (lane16&7) -> per 16-lane
// phase 8 slots x 2 lanes (free).  Read phases (row = tile*16+lane16):
// slot = (ks*4+quad) ^ (lane16&7) ^ (..) -> 8 slots x 2 lanes (free).
// Round-2 swizzle had 8-way READ conflicts (7.3M); this is conflict-free
// on both sides.
//
// k_rev folded in: s=127 row feeds a second B-operand (rev weights) for
// rev[b][h] at +4 MFMA/chunk.
// ---------------------------------------------------------------------------
__global__ __launch_bounds__(256, 4) void k_pre(
    const int* __restrict__ x, const ushort* __restrict__ embB,
    const ushort* __restrict__ wP,
    const float* __restrict__ b_ih_r, const float* __restrict__ b_hh_r,
    ushort* __restrict__ preB, float* __restrict__ rev)
{
    __shared__ int xb[IN_N];
    __shared__ __align__(16) ushort As[128 * 128];

    const int t = threadIdx.x;
    const int b = blockIdx.x;

    ((int2*)xb)[t] = ((const int2*)(x + b * IN_N))[t];
    __syncthreads();

    const int l      = t & 63;
    const int w      = t >> 6;        // wave 0..3
    const int lane16 = l & 15;        // gather/pack: 16B s-window; mfma: A-row
    const int quad   = l >> 4;        // gather/pack: row-group;   mfma: k-quad
    const int il     = w * 32 + quad * 8;   // i-position of this thread's 8 rows
    const int wg     = w * 4 + quad;        // this thread's write granule (il>>3)
    const int l7     = lane16 & 7;

    f32x4 acc[2] = {{0.f,0.f,0.f,0.f},{0.f,0.f,0.f,0.f}};
    f32x4 accR   = {0.f,0.f,0.f,0.f};

    uint R[8][4];

    // prologue: gather chunk 0 (8 rows x 16B per thread, coalesced)
    #pragma unroll
    for (int j = 0; j < 8; ++j) {
        const uint4 v = *(const uint4*)(embB + (size_t)xb[il + j] * SEQ_N + lane16 * 8);
        R[j][0] = v.x; R[j][1] = v.y; R[j][2] = v.z; R[j][3] = v.w;
    }

    for (int c = 0; c < 4; ++c) {
        // B fragments: one coalesced 16B load per lane per (c,ks), fwd+rev
        short8 bfr[4], bfrR[4];
        #pragma unroll
        for (int ks = 0; ks < 4; ++ks) {
            const ushort* wp = wP + ((size_t)(c * 4 + ks) * 128 + l) * 8;
            bfr[ks]  = *(const short8*)(wp);
            bfrR[ks] = *(const short8*)(wp + 512);
        }

        if (c) __syncthreads();   // all waves done reading previous As

        // transpose-pack: As[s = lane16*8+p][il..il+7] <- element p of 8 rows
        #pragma unroll
        for (int p = 0; p < 8; ++p) {
            const uint sel = (p & 1) ? 0x07060302u : 0x05040100u;
            const int pv = p >> 1;
            uint u0 = __builtin_amdgcn_perm(R[1][pv], R[0][pv], sel);
            uint u1 = __builtin_amdgcn_perm(R[3][pv], R[2][pv], sel);
            uint u2 = __builtin_amdgcn_perm(R[5][pv], R[4][pv], sel);
            uint u3 = __builtin_amdgcn_perm(R[7][pv], R[6][pv], sel);
            const int s    = lane16 * 8 + p;
            const int slot = wg ^ p ^ l7;          // igran ^ (s&7) ^ ((s>>3)&7)
            *(uint4*)&As[(size_t)s * 128 + (size_t)slot * 8] =
                make_uint4(u0, u1, u2, u3);
        }

        // issue next chunk's gather NOW: latency hides under barrier + MFMA
        if (c < 3) {
            const int ibase = (c + 1) * 128 + il;
            #pragma unroll
            for (int j = 0; j < 8; ++j) {
                const uint4 v = *(const uint4*)(embB + (size_t)xb[ibase + j] * SEQ_N + lane16 * 8);
                R[j][0] = v.x; R[j][1] = v.y; R[j][2] = v.z; R[j][3] = v.w;
            }
        }
        __syncthreads();

        // MFMA: 2 s-tiles per wave, 4 K-steps per chunk (+rev tile on tt=1)
        #pragma unroll
        for (int tt = 0; tt < 2; ++tt) {
            const int row = (w * 2 + tt) * 16 + lane16;
            const int fr  = (row & 7) ^ ((row >> 3) & 7);
            #pragma unroll
            for (int ks = 0; ks < 4; ++ks) {
                const int slot = (ks * 4 + quad) ^ fr;
                short8 af = *(const short8*)&As[(size_t)row * 128 + (size_t)slot * 8];
                acc[tt] = __builtin_amdgcn_mfma_f32_16x16x32_bf16(af, bfr[ks], acc[tt], 0, 0, 0);
                if (tt == 1)
                    accR = __builtin_amdgcn_mfma_f32_16x16x32_bf16(af, bfrR[ks], accR, 0, 0, 0);
            }
        }
    }

    // epilogue: D[m][n]: n = lane16 (=h), m = quad*4 + r (s within tile)
    if (lane16 < HID_N) {
        #pragma unroll
        for (int tt = 0; tt < 2; ++tt) {
            #pragma unroll
            for (int r = 0; r < 4; ++r) {
                int s = (w * 2 + tt) * 16 + quad * 4 + r;
                preB[((size_t)b * SEQ_N + s) * HP_N + lane16] = f2bf(acc[tt][r]);
            }
        }
        // rev: s=127 lives in wave 3's tt=1 tile at m=15 (quad=3, r=3)
        if (w == 3 && quad == 3)
            rev[b * HP_N + lane16] =
                fast_tanh(accR[3] + b_ih_r[lane16] + b_hh_r[lane16]);
    }
}

// ---------------------------------------------------------------------------
// k_rnn: 16 lanes per b (lane j owns hidden j), h broadcast via ds_bpermute
// (no LDS round-trip). 256 thr = 16 b per block, 128 blocks.
// ---------------------------------------------------------------------------
__global__ __launch_bounds__(256) void k_rnn(
    const ushort* __restrict__ preB, const float* __restrict__ rev,
    const float* __restrict__ w_hh_f,
    const float* __restrict__ b_ih_f, const float* __restrict__ b_hh_f,
    const float* __restrict__ fc_w, const float* __restrict__ fc_b,
    float* __restrict__ out)
{
    __shared__ float ho[16][40];

    const int tid = threadIdx.x;
    const int l   = tid & 63;
    const int j   = l & 15;
    const int jj  = (j < 12) ? j : 0;
    const int gid = tid >> 4;                 // 0..15 in block
    const int b   = blockIdx.x * 16 + gid;
    const int baseaddr = (l & 48) << 2;       // group-base lane * 4

    const float4* wr = (const float4*)(w_hh_f + jj * 12);
    float4 w0 = wr[0], w1 = wr[1], w2 = wr[2];
    float W[12] = {w0.x, w0.y, w0.z, w0.w, w1.x, w1.y, w1.z, w1.w,
                   w2.x, w2.y, w2.z, w2.w};
    const float bias = b_ih_f[jj] + b_hh_f[jj];

    const ushort* pb = preB + (size_t)b * SEQ_N * HP_N + j;
    ushort pq[8];
    #pragma unroll
    for (int k = 0; k < 8; ++k) pq[k] = pb[k * HP_N];

    float h = 0.f;
    for (int s8 = 0; s8 < 16; ++s8) {
        #pragma unroll
        for (int k = 0; k < 8; ++k) {
            int s = s8 * 8 + k;
            float p = bf2f(pq[k]) + bias;
            pq[k] = pb[((s + 8) & 127) * HP_N];     // branchless prefetch
            int hb = __float_as_int(h);
            float hk[12];
            #pragma unroll
            for (int kk = 0; kk < 12; ++kk)
                hk[kk] = __int_as_float(__builtin_amdgcn_ds_bpermute(baseaddr + 4 * kk, hb));
            float c0 = p, c1 = 0.f, c2 = 0.f;
            #pragma unroll
            for (int u = 0; u < 4; ++u) {
                c0 = __builtin_fmaf(W[u],     hk[u],     c0);
                c1 = __builtin_fmaf(W[4 + u], hk[4 + u], c1);
                c2 = __builtin_fmaf(W[8 + u], hk[8 + u], c2);
            }
            h = fast_tanh(c0 + c1 + c2);
        }
    }

    // epilogue FC (intra-wave LDS, no barrier needed)
    ho[gid][j]      = h;
    ho[gid][20 + j] = rev[b * HP_N + j];
    if (j < OUT_N) {
        const float* fw = fc_w + j * 24;
        float o = fc_b[j];
        #pragma unroll
        for (int k = 0; k < 12; ++k)
            o += fw[k] * ho[gid][k] + fw[12 + k] * ho[gid][20 + k];
        out[b * OUT_N + j] = o;
    }
}

// ---------------------------------------------------------------------------
extern "C" void kernel_launch(void* const* d_in, const int* in_sizes, int n_in,
                              void* d_out, int out_size, void* d_ws, size_t ws_size,
                              hipStream_t stream) {
    const int*   x      = (const int*)  d_in[0];
    const float* emb    = (const float*)d_in[1];
    const float* w_ih_f = (const float*)d_in[2];
    const float* w_hh_f = (const float*)d_in[3];
    const float* b_ih_f = (const float*)d_in[4];
    const float* b_hh_f = (const float*)d_in[5];
    const float* w_ih_r = (const float*)d_in[6];
    const float* b_ih_r = (const float*)d_in[8];
    const float* b_hh_r = (const float*)d_in[9];
    const float* fc_w   = (const float*)d_in[10];
    const float* fc_b   = (const float*)d_in[11];
    float* out = (float*)d_out;

    ushort* preB = (ushort*)d_ws;                              // 8 MB
    float*  rev  = (float*)((char*)d_ws + 8388608);            // 128 KB
    ushort* embB = (ushort*)((char*)d_ws + 8519680);           // 128 KB
    ushort* wP   = (ushort*)((char*)d_ws + 8650752);           // 32 KB

    k_prep<<<64,   256, 0, stream>>>(emb, w_ih_f, w_ih_r, embB, wP);
    k_pre <<<B_N,  256, 0, stream>>>(x, embB, wP, b_ih_r, b_hh_r, preB, rev);
    k_rnn <<<B_N/16,256,0, stream>>>(preB, rev, w_hh_f, b_ih_f, b_hh_f, fc_w, fc_b, out);
}

// Round 4
// 117.635 us; speedup vs baseline: 1.2788x; 1.0805x over previous
//
#include <hip/hip_runtime.h>
#include <hip/hip_bf16.h>

#define B_N     2048
#define IN_N    512
#define SEQ_N   128
#define HID_N   12
#define HP_N    16
#define OUT_N   3

typedef __attribute__((ext_vector_type(8))) short short8;
typedef __attribute__((ext_vector_type(4))) float f32x4;
typedef unsigned int uint;
typedef unsigned short ushort;

__device__ __forceinline__ float fast_tanh(float x) {
    float e = __builtin_amdgcn_exp2f(x * 2.8853900817779268f);
    return 1.0f - 2.0f * __builtin_amdgcn_rcpf(e + 1.0f);
}

__device__ __forceinline__ ushort f2bf(float f) {   // RNE fp32->bf16
    uint u = __float_as_uint(f);
    u += 0x7fffu + ((u >> 16) & 1u);
    return (ushort)(u >> 16);
}

__device__ __forceinline__ float bf2f(ushort s) {
    return __uint_as_float(((uint)s) << 16);
}

// ---------------------------------------------------------------------------
// Prep: emb (512x128 f32) -> embB bf16;
// wP = B-fragments of w_ih_f / w_ih_r pre-packed in MFMA lane order:
//   wP[cks][src][l][j]  (cks = c*4+ks, src 0=fwd 1=rev, l 0..63, j 0..7),
//   value = w[h = l&15][i = (cks>>2)*128 + (cks&3)*32 + (l>>4)*8 + j],
//   zero-padded for h >= 12.
// ---------------------------------------------------------------------------
__global__ __launch_bounds__(256) void k_prep(
    const float* __restrict__ emb, const float* __restrict__ w_ih_f,
    const float* __restrict__ w_ih_r,
    ushort* __restrict__ embB, ushort* __restrict__ wP)
{
    int tid = blockIdx.x * 256 + threadIdx.x;      // 0..16383
    float4 e = ((const float4*)emb)[tid];
    uint2 o;
    o.x = (uint)f2bf(e.x) | ((uint)f2bf(e.y) << 16);
    o.y = (uint)f2bf(e.z) | ((uint)f2bf(e.w) << 16);
    ((uint2*)embB)[tid] = o;

    // fragment pack: exactly one element per thread (16384 = 16*2*64*8)
    int j   = tid & 7;
    int l   = (tid >> 3) & 63;
    int src = (tid >> 9) & 1;
    int cks = tid >> 10;                           // 0..15
    int h   = l & 15;
    int i   = (cks >> 2) * 128 + (cks & 3) * 32 + (l >> 4) * 8 + j;
    const float* wsrc = src ? w_ih_r : w_ih_f;
    wP[(((size_t)cks * 2 + src) * 64 + l) * 8 + j] =
        (h < HID_N) ? f2bf(wsrc[h * IN_N + i]) : (ushort)0;
}

// ---------------------------------------------------------------------------
// k_pre v4: persistent blocks (512 blocks x 4 b), raw-barrier pipeline.
//
// Why: __syncthreads drains vmcnt(0) before s_barrier, so the prefetched
// gather's L2 latency was fully exposed 8x/block.  Here barriers are raw
// s_barrier + lgkmcnt(0) only -> gathers stay in flight across the publish
// barrier; the compiler's counted vmcnt wait lands at the NEXT phase's
// pack, after ~barrier + 8 ds_read + 12 MFMA have covered the latency.
//
// wP staged once per block into LDS (was: 32 global dwordx4 /thread /b =
// 64 MB redundant L2 traffic).  Index words loaded per-thread directly
// (broadcast-coalesced), prefetched one phase ahead.
//
// As layout identical to round 3 (dual-XOR swizzle, conflict-free both
// sides).  Math bit-identical to round 3.
// LDS 64 KB -> 2 blocks/CU.
// ---------------------------------------------------------------------------
__global__ __launch_bounds__(256, 2) void k_pre(
    const int* __restrict__ x, const ushort* __restrict__ embB,
    const ushort* __restrict__ wP,
    const float* __restrict__ b_ih_r, const float* __restrict__ b_hh_r,
    ushort* __restrict__ preB, float* __restrict__ rev)
{
    __shared__ __align__(16) ushort As[128 * 128];     // 32 KB
    __shared__ __align__(16) ushort wPs[16384];        // 32 KB

    const int t      = threadIdx.x;
    const int l      = t & 63;
    const int w      = t >> 6;        // wave 0..3
    const int lane16 = l & 15;        // gather/pack: 16B s-window; mfma: A-row
    const int quad   = l >> 4;        // gather/pack: row-group;   mfma: k-quad
    const int il     = w * 32 + quad * 8;   // i-position of this thread's 8 rows
    const int wg     = w * 4 + quad;        // write granule (il>>3)
    const int l7     = lane16 & 7;
    const int so     = lane16 * 8;          // s-offset within row (ushorts)
    const int b0     = blockIdx.x * 4;

    // ---- stage packed weights into LDS (once per block, coalesced) ----
    {
        const uint4* s4 = (const uint4*)wP;
        uint4*       d4 = (uint4*)wPs;
        #pragma unroll
        for (int i = 0; i < 8; ++i) d4[t + i * 256] = s4[t + i * 256];
    }
    // (first weight READ is after the first publish barrier -> visible)

    f32x4 acc0 = {0.f,0.f,0.f,0.f};
    f32x4 acc1 = {0.f,0.f,0.f,0.f};
    f32x4 accR = {0.f,0.f,0.f,0.f};
    uint R[8][4];

#define LD8(k, ix) { uint4 v = *(const uint4*)(embB + (size_t)(ix) * SEQ_N + so); \
        R[k][0]=v.x; R[k][1]=v.y; R[k][2]=v.z; R[k][3]=v.w; }

    // idx regs for phase 0, then gather phase 0 (prologue; latency exposed once)
    int4 nA, nB;
    {
        const int* xq = x + (size_t)b0 * IN_N + il;
        nA = *(const int4*)xq;
        nB = *(const int4*)(xq + 4);
    }
    LD8(0, nA.x) LD8(1, nA.y) LD8(2, nA.z) LD8(3, nA.w)
    LD8(4, nB.x) LD8(5, nB.y) LD8(6, nB.z) LD8(7, nB.w)
    {   // idx for phase 1
        const int* xq = x + (size_t)b0 * IN_N + 128 + il;
        nA = *(const int4*)xq;
        nB = *(const int4*)(xq + 4);
    }

    for (int p = 0; p < 16; ++p) {     // phase: b = b0 + (p>>2), chunk c = p&3
        const int c = p & 3;

        // ---- transpose-pack R -> As (compiler inserts counted vmcnt wait) ----
        #pragma unroll
        for (int pp = 0; pp < 8; ++pp) {
            const uint sel = (pp & 1) ? 0x07060302u : 0x05040100u;
            const int pv = pp >> 1;
            uint u0 = __builtin_amdgcn_perm(R[1][pv], R[0][pv], sel);
            uint u1 = __builtin_amdgcn_perm(R[3][pv], R[2][pv], sel);
            uint u2 = __builtin_amdgcn_perm(R[5][pv], R[4][pv], sel);
            uint u3 = __builtin_amdgcn_perm(R[7][pv], R[6][pv], sel);
            const int s    = lane16 * 8 + pp;
            const int slot = wg ^ pp ^ l7;      // igran ^ (s&7) ^ ((s>>3)&7)
            *(uint4*)&As[(size_t)s * 128 + (size_t)slot * 8] =
                make_uint4(u0, u1, u2, u3);
        }

        // ---- issue next phase's gather + idx prefetch (stay in flight) ----
        if (p < 15) {
            LD8(0, nA.x) LD8(1, nA.y) LD8(2, nA.z) LD8(3, nA.w)
            LD8(4, nB.x) LD8(5, nB.y) LD8(6, nB.z) LD8(7, nB.w)
            if (p < 14) {
                const int pn = p + 2;
                const int* xq = x + (size_t)(b0 + (pn >> 2)) * IN_N
                                  + (pn & 3) * 128 + il;
                nA = *(const int4*)xq;
                nB = *(const int4*)(xq + 4);
            }
        }

        // ---- publish As(p): LDS-drain + raw barrier (NO vmcnt drain) ----
        asm volatile("s_waitcnt lgkmcnt(0)" ::: "memory");
        __builtin_amdgcn_s_barrier();
        __builtin_amdgcn_sched_barrier(0);

        // ---- weights for this chunk from LDS ----
        short8 bfr[4], bfrR[4];
        #pragma unroll
        for (int ks = 0; ks < 4; ++ks) {
            const ushort* wp = wPs + (size_t)((c * 4 + ks) * 128 + l) * 8;
            bfr[ks]  = *(const short8*)wp;
            bfrR[ks] = *(const short8*)(wp + 512);
        }

        // ---- MFMA: 2 s-tiles, 4 K-steps (+rev tile on tt=1) ----
        #pragma unroll
        for (int tt = 0; tt < 2; ++tt) {
            const int row = (w * 2 + tt) * 16 + lane16;
            const int fr  = (row & 7) ^ ((row >> 3) & 7);
            #pragma unroll
            for (int ks = 0; ks < 4; ++ks) {
                const int slot = (ks * 4 + quad) ^ fr;
                short8 af = *(const short8*)&As[(size_t)row * 128 + (size_t)slot * 8];
                if (tt == 0) {
                    acc0 = __builtin_amdgcn_mfma_f32_16x16x32_bf16(af, bfr[ks], acc0, 0, 0, 0);
                } else {
                    acc1 = __builtin_amdgcn_mfma_f32_16x16x32_bf16(af, bfr[ks], acc1, 0, 0, 0);
                    accR = __builtin_amdgcn_mfma_f32_16x16x32_bf16(af, bfrR[ks], accR, 0, 0, 0);
                }
            }
        }

        // ---- per-b epilogue (stores are fire-and-forget) ----
        if (c == 3) {
            const int bcur = b0 + (p >> 2);
            if (lane16 < HID_N) {
                #pragma unroll
                for (int r = 0; r < 4; ++r) {
                    const int s0v = (w * 2 + 0) * 16 + quad * 4 + r;
                    preB[((size_t)bcur * SEQ_N + s0v) * HP_N + lane16] = f2bf(acc0[r]);
                    const int s1v = (w * 2 + 1) * 16 + quad * 4 + r;
                    preB[((size_t)bcur * SEQ_N + s1v) * HP_N + lane16] = f2bf(acc1[r]);
                }
                // rev: s=127 lives in wave 3's tt=1 tile at m=15 (quad=3, r=3)
                if (w == 3 && quad == 3)
                    rev[bcur * HP_N + lane16] =
                        fast_tanh(accR[3] + b_ih_r[lane16] + b_hh_r[lane16]);
            }
            acc0 = (f32x4){0.f,0.f,0.f,0.f};
            acc1 = (f32x4){0.f,0.f,0.f,0.f};
            accR = (f32x4){0.f,0.f,0.f,0.f};
        }

        // ---- consumed barrier: As free for next pack ----
        asm volatile("" ::: "memory");
        __builtin_amdgcn_s_barrier();
        __builtin_amdgcn_sched_barrier(0);
    }
#undef LD8
}

// ---------------------------------------------------------------------------
// k_rnn: 16 lanes per b (lane j owns hidden j), h broadcast via ds_bpermute
// (no LDS round-trip). 256 thr = 16 b per block, 128 blocks.
// ---------------------------------------------------------------------------
__global__ __launch_bounds__(256) void k_rnn(
    const ushort* __restrict__ preB, const float* __restrict__ rev,
    const float* __restrict__ w_hh_f,
    const float* __restrict__ b_ih_f, const float* __restrict__ b_hh_f,
    const float* __restrict__ fc_w, const float* __restrict__ fc_b,
    float* __restrict__ out)
{
    __shared__ float ho[16][40];

    const int tid = threadIdx.x;
    const int l   = tid & 63;
    const int j   = l & 15;
    const int jj  = (j < 12) ? j : 0;
    const int gid = tid >> 4;                 // 0..15 in block
    const int b   = blockIdx.x * 16 + gid;
    const int baseaddr = (l & 48) << 2;       // group-base lane * 4

    const float4* wr = (const float4*)(w_hh_f + jj * 12);
    float4 w0 = wr[0], w1 = wr[1], w2 = wr[2];
    float W[12] = {w0.x, w0.y, w0.z, w0.w, w1.x, w1.y, w1.z, w1.w,
                   w2.x, w2.y, w2.z, w2.w};
    const float bias = b_ih_f[jj] + b_hh_f[jj];

    const ushort* pb = preB + (size_t)b * SEQ_N * HP_N + j;
    ushort pq[8];
    #pragma unroll
    for (int k = 0; k < 8; ++k) pq[k] = pb[k * HP_N];

    float h = 0.f;
    for (int s8 = 0; s8 < 16; ++s8) {
        #pragma unroll
        for (int k = 0; k < 8; ++k) {
            int s = s8 * 8 + k;
            float p = bf2f(pq[k]) + bias;
            pq[k] = pb[((s + 8) & 127) * HP_N];     // branchless prefetch
            int hb = __float_as_int(h);
            float hk[12];
            #pragma unroll
            for (int kk = 0; kk < 12; ++kk)
                hk[kk] = __int_as_float(__builtin_amdgcn_ds_bpermute(baseaddr + 4 * kk, hb));
            float c0 = p, c1 = 0.f, c2 = 0.f;
            #pragma unroll
            for (int u = 0; u < 4; ++u) {
                c0 = __builtin_fmaf(W[u],     hk[u],     c0);
                c1 = __builtin_fmaf(W[4 + u], hk[4 + u], c1);
                c2 = __builtin_fmaf(W[8 + u], hk[8 + u], c2);
            }
            h = fast_tanh(c0 + c1 + c2);
        }
    }

    // epilogue FC (intra-wave LDS, no barrier needed)
    ho[gid][j]      = h;
    ho[gid][20 + j] = rev[b * HP_N + j];
    if (j < OUT_N) {
        const float* fw = fc_w + j * 24;
        float o = fc_b[j];
        #pragma unroll
        for (int k = 0; k < 12; ++k)
            o += fw[k] * ho[gid][k] + fw[12 + k] * ho[gid][20 + k];
        out[b * OUT_N + j] = o;
    }
}

// ---------------------------------------------------------------------------
extern "C" void kernel_launch(void* const* d_in, const int* in_sizes, int n_in,
                              void* d_out, int out_size, void* d_ws, size_t ws_size,
                              hipStream_t stream) {
    const int*   x      = (const int*)  d_in[0];
    const float* emb    = (const float*)d_in[1];
    const float* w_ih_f = (const float*)d_in[2];
    const float* w_hh_f = (const float*)d_in[3];
    const float* b_ih_f = (const float*)d_in[4];
    const float* b_hh_f = (const float*)d_in[5];
    const float* w_ih_r = (const float*)d_in[6];
    const float* b_ih_r = (const float*)d_in[8];
    const float* b_hh_r = (const float*)d_in[9];
    const float* fc_w   = (const float*)d_in[10];
    const float* fc_b   = (const float*)d_in[11];
    float* out = (float*)d_out;

    ushort* preB = (ushort*)d_ws;                              // 8 MB
    float*  rev  = (float*)((char*)d_ws + 8388608);            // 128 KB
    ushort* embB = (ushort*)((char*)d_ws + 8519680);           // 128 KB
    ushort* wP   = (ushort*)((char*)d_ws + 8650752);           // 32 KB

    k_prep<<<64,    256, 0, stream>>>(emb, w_ih_f, w_ih_r, embB, wP);
    k_pre <<<B_N/4, 256, 0, stream>>>(x, embB, wP, b_ih_r, b_hh_r, preB, rev);
    k_rnn <<<B_N/16,256, 0, stream>>>(preB, rev, w_hh_f, b_ih_f, b_hh_f, fc_w, fc_b, out);
}